// Round 10
// baseline (132.080 us; speedup 1.0000x reference)
//
#include <hip/hip_runtime.h>
#include <stdint.h>

// MultiHeadedSelfAttention: B=4, C=256, S=4096, O=256, H=4, D=64
// softmax over axis -2  =>  scores^T is standard flash attn with Qfa=K, Kfa=Q.
// R9: (1) l-sum moved from ones-MFMA (4/20 of MFMA pipe) to VALU f32 accumulate
//     (32 adds/iter) + end reduction. (2) cvtX rewritten with float4 loads.

#define S_LEN 4096
#define HD 64
#define LOG2E 1.44269504088896f

typedef __attribute__((ext_vector_type(8))) __bf16 bf16x8;
typedef __attribute__((ext_vector_type(8))) unsigned short u16x8;
typedef __attribute__((ext_vector_type(4))) float f32x4;
typedef __attribute__((ext_vector_type(16))) float f32x16;
typedef __attribute__((ext_vector_type(4))) unsigned int u32x4;

__device__ __forceinline__ unsigned short f2bf(float f) {
    unsigned int u = __float_as_uint(f);
    u = (u + 0x7FFFu + ((u >> 16) & 1u)) >> 16;
    return (unsigned short)u;
}

__device__ __forceinline__ unsigned int cvt_pk_bf16(float lo, float hi) {
    unsigned int r;
    asm("v_cvt_pk_bf16_f32 %0, %1, %2" : "=v"(r) : "v"(lo), "v"(hi));
    return r;
}

// swaps a[32:63] <-> b[0:31]. ONLY safe when a and b hold distinct values
// (distinct registers) — proven in the v5 P-fragment path.
#define PLSWAP(a, b) asm volatile("v_permlane32_swap_b32 %0, %1" : "+v"(a), "+v"(b))

__device__ __forceinline__ void gl16(const void* g, void* l) {
    __builtin_amdgcn_global_load_lds(
        (const __attribute__((address_space(1))) unsigned int*)g,
        (__attribute__((address_space(3))) unsigned int*)l, 16, 0, 0);
}

// ---------------- X f32 [B,C,S] -> Xt bf16 [B*S, C] (float4 reads) ----------------
// grid 1024 = b(4) x st(64) x ct(4); block 256
__global__ __launch_bounds__(256) void cvtX(const float* __restrict__ X,
                                            unsigned short* __restrict__ Xh) {
    __shared__ float LT[64][65];   // [s][c], +1 pad: write 2-way conflict (free)
    int tid = threadIdx.x;
    int id = blockIdx.x;
    int ct = id & 3;
    int st = (id >> 2) & 63;
    int b  = id >> 8;
    int sseg = (tid & 15) * 4;
    int crow = tid >> 4;
    const float* Xp = X + ((size_t)b << 20) + st * 64 + sseg;
#pragma unroll
    for (int p = 0; p < 4; p++) {
        int c = crow + p * 16;
        float4 v = *(const float4*)(Xp + ((size_t)(ct * 64 + c) << 12));
        LT[sseg + 0][c] = v.x;
        LT[sseg + 1][c] = v.y;
        LT[sseg + 2][c] = v.z;
        LT[sseg + 3][c] = v.w;
    }
    __syncthreads();
    int s = tid >> 2, cseg = (tid & 3) * 16;
    size_t ob = ((size_t)(b * S_LEN + st * 64 + s)) * 256 + ct * 64 + cseg;
#pragma unroll
    for (int hh = 0; hh < 2; hh++) {
        u16x8 vh;
#pragma unroll
        for (int i = 0; i < 8; i++) vh[i] = f2bf(LT[s][cseg + hh * 8 + i]);
        *(u16x8*)(Xh + ob + hh * 8) = vh;
    }
}

// ---------------- W f32 -> bf16. Wb layout [z][65536] ----------------
__global__ __launch_bounds__(256) void cvtW(const float* __restrict__ Wq,
                                            const float* __restrict__ Wk,
                                            const float* __restrict__ Wv,
                                            unsigned short* __restrict__ Wb) {
    int id = blockIdx.x;
    int z = id >> 5, blk = id & 31;
    const float* src = (z == 0) ? Wq : ((z == 1) ? Wk : Wv);
    int base = blk * 2048 + threadIdx.x * 8;
    u16x8 vh;
#pragma unroll
    for (int i = 0; i < 8; i++) vh[i] = f2bf(src[base + i]);
    *(u16x8*)(Wb + (size_t)z * 65536 + base) = vh;
}

// ---------------- projection GEMM (pure bf16): D[s,o] = Xt[s,:] . W[o,:]^T + b ----
__global__ __launch_bounds__(256) void proj_gemm(
    const unsigned short* __restrict__ Xh,
    const unsigned short* __restrict__ Wb,
    const float* __restrict__ bq, const float* __restrict__ bk, const float* __restrict__ bv,
    unsigned short* __restrict__ Qt, unsigned short* __restrict__ Kt,
    unsigned short* __restrict__ Vn) {
    int tid = threadIdx.x, lane = tid & 63, wv = tid >> 6;
    int l16 = lane & 15, lg = lane >> 4;
    int bid = blockIdx.x;
    int z = bid / 512;
    int r = bid % 512;
    int mBlk = r & 127, oBlk = r >> 7;

    const float* bias = (z == 0) ? bq : ((z == 1) ? bk : bv);
    const unsigned short* Wh = Wb + (size_t)z * 65536;

    int sBase = mBlk * 128 + (wv & 1) * 64;
    int oBase = oBlk * 64 + (wv >> 1) * 32;

    f32x4 acc[4][2] = {};

    const unsigned short* Ah_p = Xh + (size_t)(sBase + l16) * 256 + lg * 8;
    const unsigned short* Bh_p = Wh + (size_t)(oBase + l16) * 256 + lg * 8;

    for (int kk = 0; kk < 8; kk++) {
        int ko = kk * 32;
        bf16x8 ah[4], bh[2];
#pragma unroll
        for (int mt = 0; mt < 4; mt++)
            ah[mt] = *(const bf16x8*)(Ah_p + mt * 16 * 256 + ko);
#pragma unroll
        for (int nt = 0; nt < 2; nt++)
            bh[nt] = *(const bf16x8*)(Bh_p + nt * 16 * 256 + ko);
#pragma unroll
        for (int mt = 0; mt < 4; mt++)
#pragma unroll
            for (int nt = 0; nt < 2; nt++)
                acc[mt][nt] = __builtin_amdgcn_mfma_f32_16x16x32_bf16(ah[mt], bh[nt], acc[mt][nt], 0, 0, 0);
    }

    float b0 = bias[oBase + l16];
    float b1 = bias[oBase + 16 + l16];
    int b = mBlk >> 5;

    if (z < 2) {
        unsigned short* dst = (z == 0) ? Qt : Kt;
        float sc = (z == 1) ? (0.125f * LOG2E) : 1.0f;
        int head = oBlk;
        int d0 = (wv >> 1) * 32 + l16;
        size_t rowbase = ((size_t)(b * 4 + head)) * S_LEN;
#pragma unroll
        for (int mt = 0; mt < 4; mt++)
#pragma unroll
            for (int j = 0; j < 4; j++) {
                int s = (mBlk & 31) * 128 + (wv & 1) * 64 + mt * 16 + lg * 4 + j;
                size_t off = (rowbase + s) * HD;
                dst[off + d0]      = f2bf((acc[mt][0][j] + b0) * sc);
                dst[off + d0 + 16] = f2bf((acc[mt][1][j] + b1) * sc);
            }
    } else {
        // V -> tiled layout [bh][sTile(64)][d(64)][64] via LDS transpose
        __shared__ unsigned short TL[64][136];
        int o0l = (wv >> 1) * 32 + l16;
#pragma unroll
        for (int mt = 0; mt < 4; mt++) {
            int sl = (wv & 1) * 64 + mt * 16 + lg * 4;
            *(unsigned int*)&TL[o0l][sl]          = cvt_pk_bf16(acc[mt][0][0] + b0, acc[mt][0][1] + b0);
            *(unsigned int*)&TL[o0l][sl + 2]      = cvt_pk_bf16(acc[mt][0][2] + b0, acc[mt][0][3] + b0);
            *(unsigned int*)&TL[o0l + 16][sl]     = cvt_pk_bf16(acc[mt][1][0] + b1, acc[mt][1][1] + b1);
            *(unsigned int*)&TL[o0l + 16][sl + 2] = cvt_pk_bf16(acc[mt][1][2] + b1, acc[mt][1][3] + b1);
        }
        __syncthreads();
        int ol = tid >> 2, sc0 = (tid & 3) * 32;
        int bhIdx = b * 4 + oBlk;
        int sbase = (mBlk & 31) * 128 + sc0;
        size_t obase = (size_t)bhIdx * 262144 + (size_t)ol * 64;
#pragma unroll
        for (int u = 0; u < 4; u++) {
            int s = sbase + u * 8;
            size_t addr = obase + (size_t)(s >> 6) * 4096 + (s & 63);
            u16x8 v = *(u16x8*)&TL[ol][sc0 + u * 8];
            *(u16x8*)(Vn + addr) = v;
        }
    }
}

// ---------------- flash attention v10: VALU l-sum (no ones-MFMA) ----------------
// grid 512 = bh(16) x tblk(32) (XCD-swizzled); block 512 = 2 s-groups x 4 t-subwaves
// LDS 64KB: Q[g][p] at g*16K + p*8K; V[g][p] at 32K + g*16K + p*8K
__global__ __launch_bounds__(512, 4) void attn_v10(const unsigned short* __restrict__ Qt,
                                                   const unsigned short* __restrict__ Kt,
                                                   const unsigned short* __restrict__ Vt2,
                                                   float* __restrict__ out) {
    __shared__ __align__(16) char smem[65536];
    int tid = threadIdx.x, lane = tid & 63, wv = tid >> 6;
    int l31 = lane & 31, h = lane >> 5;
    int g = wv >> 2, ws = wv & 3;

    int blk = blockIdx.x;
    int swz = (blk & 7) * 64 + (blk >> 3);   // 512 % 8 == 0: bijective
    int tblk = swz & 31, bh = swz >> 5;
    int t0 = tblk * 128 + ws * 32;

    // K fragments (B-operand): col t = t0+l31, k(d) = u*16 + h*8 + i (one-time gather)
    const unsigned short* kp = Kt + ((size_t)bh * S_LEN + t0 + l31) * HD + h * 8;
    bf16x8 kf[4];
#pragma unroll
    for (int u = 0; u < 4; u++) kf[u] = *(const bf16x8*)(kp + u * 16);

    const char* Qg = (const char*)(Qt + (size_t)bh * S_LEN * HD);   // 8KB per s-tile
    const char* Vg = (const char*)(Vt2 + (size_t)bh * 262144);      // 8KB per s-tile

    // staging: the 4 waves of a group stage their group's Q+V tile (2KB each)
    // LDS content XOR-chunk-swizzled: LDS[row][c] = G[row][c^(row&7)]
    int pos0 = ws * 2048 + lane * 16;
    int pos1 = pos0 + 1024;
    int r0 = pos0 >> 7, c0 = (pos0 >> 4) & 7;
    int r1 = pos1 >> 7, c1 = (pos1 >> 4) & 7;
    int src0 = r0 * 128 + ((c0 ^ (r0 & 7)) << 4);
    int src1 = r1 * 128 + ((c1 ^ (r1 & 7)) << 4);

    char* Qbase = smem + g * 16384;
    char* Vbase = smem + 32768 + g * 16384;

    // fragment read chunk offsets: chunk (u*2+h) of row l31, swizzled by row&7
    const int rx = l31 & 7;
    int ch[4];
#pragma unroll
    for (int u = 0; u < 4; u++) ch[u] = (((u * 2 + h) ^ rx) << 4);
    const int rowb = l31 * 128;   // + 4096 for rows 32..63

    f32x16 oacc0 = {}, oacc1 = {}, lsumv = {};
    const f32x16 ZV = {};        // loop-invariant zero C-operand

#define STAGE10(p, t) do {                                  \
        const char* qg_ = Qg + (size_t)(t) * 8192;          \
        const char* vg_ = Vg + (size_t)(t) * 8192;          \
        gl16(qg_ + src0, Qbase + (p) * 8192 + ws * 2048);         \
        gl16(qg_ + src1, Qbase + (p) * 8192 + ws * 2048 + 1024);  \
        gl16(vg_ + src0, Vbase + (p) * 8192 + ws * 2048);         \
        gl16(vg_ + src1, Vbase + (p) * 8192 + ws * 2048 + 1024);  \
    } while (0)

    STAGE10(0, g);                 // group g's first tile
    __syncthreads();

    for (int it = 0; it < 32; ++it) {
        char* Qb = Qbase + (it & 1) * 8192;
        char* Vb = Vbase + (it & 1) * 8192;
        if (it < 31) STAGE10((it & 1) ^ 1, 2 * it + 2 + g);

        // ---- QK^T: D[s_row, t_col], two 32-row halves (log2-domain, K pre-scaled) ----
        __builtin_amdgcn_s_setprio(1);
        f32x16 s0, s1;
        {
            bf16x8 q = *(const bf16x8*)(Qb + rowb + ch[0]);
            s0 = __builtin_amdgcn_mfma_f32_32x32x16_bf16(q, kf[0], ZV, 0, 0, 0);
        }
#pragma unroll
        for (int u = 1; u < 4; u++) {
            bf16x8 q = *(const bf16x8*)(Qb + rowb + ch[u]);
            s0 = __builtin_amdgcn_mfma_f32_32x32x16_bf16(q, kf[u], s0, 0, 0, 0);
        }
        {
            bf16x8 q = *(const bf16x8*)(Qb + 4096 + rowb + ch[0]);
            s1 = __builtin_amdgcn_mfma_f32_32x32x16_bf16(q, kf[0], ZV, 0, 0, 0);
        }
#pragma unroll
        for (int u = 1; u < 4; u++) {
            bf16x8 q = *(const bf16x8*)(Qb + 4096 + rowb + ch[u]);
            s1 = __builtin_amdgcn_mfma_f32_32x32x16_bf16(q, kf[u], s1, 0, 0, 0);
        }
        __builtin_amdgcn_s_setprio(0);

        // ---- P = exp2(s) raw (v_exp_f32): common scale cancels in the ratio ----
#pragma unroll
        for (int r = 0; r < 16; r++) {
            s0[r] = __builtin_amdgcn_exp2f(s0[r]);
            s1[r] = __builtin_amdgcn_exp2f(s1[r]);
        }

        // ---- denominator accumulates on the VALU pipe (f32, reduced at end) ----
        lsumv += s0;
        lsumv += s1;

        // ---- P -> bf16 B-fragments in-register (cvt_pk + permlane32_swap) ----
        unsigned int W0[4][2], W1[4][2];
#pragma unroll
        for (int q = 0; q < 4; q++)
#pragma unroll
            for (int ip = 0; ip < 2; ip++) {
                W0[q][ip] = cvt_pk_bf16(s0[4 * q + 2 * ip], s0[4 * q + 2 * ip + 1]);
                W1[q][ip] = cvt_pk_bf16(s1[4 * q + 2 * ip], s1[4 * q + 2 * ip + 1]);
            }
        u32x4 pw0, pw1, pw2, pw3;
        {
            unsigned int a0 = W0[0][0], b0 = W0[1][0]; PLSWAP(a0, b0);
            unsigned int a1 = W0[0][1], b1 = W0[1][1]; PLSWAP(a1, b1);
            pw0 = (u32x4){a0, a1, b0, b1};
            unsigned int c0s = W0[2][0], d0s = W0[3][0]; PLSWAP(c0s, d0s);
            unsigned int c1s = W0[2][1], d1s = W0[3][1]; PLSWAP(c1s, d1s);
            pw1 = (u32x4){c0s, c1s, d0s, d1s};
            unsigned int e0 = W1[0][0], f0 = W1[1][0]; PLSWAP(e0, f0);
            unsigned int e1 = W1[0][1], f1 = W1[1][1]; PLSWAP(e1, f1);
            pw2 = (u32x4){e0, e1, f0, f1};
            unsigned int g0 = W1[2][0], h0 = W1[3][0]; PLSWAP(g0, h0);
            unsigned int g1 = W1[2][1], h1 = W1[3][1]; PLSWAP(g1, h1);
            pw3 = (u32x4){g0, g1, h0, h1};
        }
        bf16x8 pb0 = *(bf16x8*)&pw0, pb1 = *(bf16x8*)&pw1;
        bf16x8 pb2 = *(bf16x8*)&pw2, pb3 = *(bf16x8*)&pw3;

        // ---- O += V . P (D[d_row, t_col]) ----
        __builtin_amdgcn_s_setprio(1);
#pragma unroll
        for (int b2 = 0; b2 < 4; b2++) {
            bf16x8 pb = (b2 == 0) ? pb0 : (b2 == 1) ? pb1 : (b2 == 2) ? pb2 : pb3;
            bf16x8 v0 = *(const bf16x8*)(Vb + rowb + ch[b2]);
            bf16x8 v1 = *(const bf16x8*)(Vb + 4096 + rowb + ch[b2]);
            oacc0 = __builtin_amdgcn_mfma_f32_32x32x16_bf16(v0, pb, oacc0, 0, 0, 0);
            oacc1 = __builtin_amdgcn_mfma_f32_32x32x16_bf16(v1, pb, oacc1, 0, 0, 0);
        }
        __builtin_amdgcn_s_setprio(0);

        __syncthreads();  // staged tile ready (vmcnt drained) + reads of Qb/Vb done
    }

    // ---- reduce denominator: in-lane 16 + cross-half ----
    float l_lane = 0.f;
#pragma unroll
    for (int r = 0; r < 16; r++) l_lane += lsumv[r];
    float l = l_lane + __shfl_xor(l_lane, 32);

    // ---- merge the two s-groups via LDS (plain sums — no max state) ----
    if (g == 1) {
        float* ml = (float*)(smem + ws * 256);
        ml[lane] = l;
        float* ob = (float*)(smem + 32768 + ws * 8192) + lane * 32;
#pragma unroll
        for (int r = 0; r < 16; r++) {
            ob[(((r >> 2) ^ rx) << 2) + (r & 3)]       = oacc0[r];
            ob[((((r >> 2) + 4) ^ rx) << 2) + (r & 3)] = oacc1[r];
        }
    }
    __syncthreads();
    if (g == 0) {
        const float* ml = (const float*)(smem + ws * 256);
        float lB = ml[lane];
        const float* ob = (const float*)(smem + 32768 + ws * 8192) + lane * 32;
        float rinv = 1.0f / (l + lB);

        float* op = out + (size_t)(bh * 64) * S_LEN + t0 + l31;
#pragma unroll
        for (int r = 0; r < 16; r++) {
            int d = (r & 3) + 8 * (r >> 2) + 4 * h;
            float vB0 = ob[(((r >> 2) ^ rx) << 2) + (r & 3)];
            float vB1 = ob[((((r >> 2) + 4) ^ rx) << 2) + (r & 3)];
            op[(size_t)d * S_LEN]        = (oacc0[r] + vB0) * rinv;
            op[(size_t)(d + 32) * S_LEN] = (oacc1[r] + vB1) * rinv;
        }
    }
}

extern "C" void kernel_launch(void* const* d_in, const int* in_sizes, int n_in,
                              void* d_out, int out_size, void* d_ws, size_t ws_size,
                              hipStream_t stream) {
    const float* X  = (const float*)d_in[0];
    const float* Wq = (const float*)d_in[1];
    const float* bq = (const float*)d_in[2];
    const float* Wk = (const float*)d_in[3];
    const float* bk = (const float*)d_in[4];
    const float* Wv = (const float*)d_in[5];
    const float* bv = (const float*)d_in[6];
    float* out = (float*)d_out;

    const size_t ELEMS = (size_t)16 * S_LEN * HD;
    unsigned short* Qt = (unsigned short*)d_ws;
    unsigned short* Kt = Qt + ELEMS;
    unsigned short* Vn = Kt + ELEMS;
    unsigned short* Wb = Vn + ELEMS;   // 3*65536 u16

    unsigned short* Xh = (unsigned short*)d_out;   // consumed before attn writes out

    cvtX<<<1024, 256, 0, stream>>>(X, Xh);
    cvtW<<<96, 256, 0, stream>>>(Wq, Wk, Wv, Wb);
    proj_gemm<<<1536, 256, 0, stream>>>(Xh, Wb, bq, bk, bv, Qt, Kt, Vn);
    attn_v10<<<512, 512, 0, stream>>>(Qt, Kt, Vn, out);
}

// Round 11
// 118.503 us; speedup vs baseline: 1.1146x; 1.1146x over previous
//
#include <hip/hip_runtime.h>
#include <stdint.h>

// MultiHeadedSelfAttention: B=4, C=256, S=4096, O=256, H=4, D=64
// softmax over axis -2  =>  scores^T is standard flash attn with Qfa=K, Kfa=Q.
// R10: (1) revert l-sum to ones-MFMA (v9 form; MFMA pipe had slack, VALU did not).
//      (2) LDS tiles re-laid out [chunk][row] via pre-permuted gl16 source ->
//          ds_read_b128 is two contiguous 512B runs, zero bank conflicts.
//      (3) proj: 3 z-GEMMs fused into one block (Xh tile read once, L2-hot).

#define S_LEN 4096
#define HD 64
#define LOG2E 1.44269504088896f

typedef __attribute__((ext_vector_type(8))) __bf16 bf16x8;
typedef __attribute__((ext_vector_type(8))) unsigned short u16x8;
typedef __attribute__((ext_vector_type(4))) float f32x4;
typedef __attribute__((ext_vector_type(16))) float f32x16;
typedef __attribute__((ext_vector_type(4))) unsigned int u32x4;

__device__ __forceinline__ unsigned short f2bf(float f) {
    unsigned int u = __float_as_uint(f);
    u = (u + 0x7FFFu + ((u >> 16) & 1u)) >> 16;
    return (unsigned short)u;
}

__device__ __forceinline__ unsigned int cvt_pk_bf16(float lo, float hi) {
    unsigned int r;
    asm("v_cvt_pk_bf16_f32 %0, %1, %2" : "=v"(r) : "v"(lo), "v"(hi));
    return r;
}

// swaps a[32:63] <-> b[0:31]. ONLY safe when a and b hold distinct values
// (distinct registers) — proven in the v5 P-fragment path.
#define PLSWAP(a, b) asm volatile("v_permlane32_swap_b32 %0, %1" : "+v"(a), "+v"(b))

__device__ __forceinline__ void gl16(const void* g, void* l) {
    __builtin_amdgcn_global_load_lds(
        (const __attribute__((address_space(1))) unsigned int*)g,
        (__attribute__((address_space(3))) unsigned int*)l, 16, 0, 0);
}

// ---------------- X f32 [B,C,S] -> Xt bf16 [B*S, C] (float4 reads) ----------------
__global__ __launch_bounds__(256) void cvtX(const float* __restrict__ X,
                                            unsigned short* __restrict__ Xh) {
    __shared__ float LT[64][65];
    int tid = threadIdx.x;
    int id = blockIdx.x;
    int ct = id & 3;
    int st = (id >> 2) & 63;
    int b  = id >> 8;
    int sseg = (tid & 15) * 4;
    int crow = tid >> 4;
    const float* Xp = X + ((size_t)b << 20) + st * 64 + sseg;
#pragma unroll
    for (int p = 0; p < 4; p++) {
        int c = crow + p * 16;
        float4 v = *(const float4*)(Xp + ((size_t)(ct * 64 + c) << 12));
        LT[sseg + 0][c] = v.x;
        LT[sseg + 1][c] = v.y;
        LT[sseg + 2][c] = v.z;
        LT[sseg + 3][c] = v.w;
    }
    __syncthreads();
    int s = tid >> 2, cseg = (tid & 3) * 16;
    size_t ob = ((size_t)(b * S_LEN + st * 64 + s)) * 256 + ct * 64 + cseg;
#pragma unroll
    for (int hh = 0; hh < 2; hh++) {
        u16x8 vh;
#pragma unroll
        for (int i = 0; i < 8; i++) vh[i] = f2bf(LT[s][cseg + hh * 8 + i]);
        *(u16x8*)(Xh + ob + hh * 8) = vh;
    }
}

// ---------------- W f32 -> bf16. Wb layout [z][65536] ----------------
__global__ __launch_bounds__(256) void cvtW(const float* __restrict__ Wq,
                                            const float* __restrict__ Wk,
                                            const float* __restrict__ Wv,
                                            unsigned short* __restrict__ Wb) {
    int id = blockIdx.x;
    int z = id >> 5, blk = id & 31;
    const float* src = (z == 0) ? Wq : ((z == 1) ? Wk : Wv);
    int base = blk * 2048 + threadIdx.x * 8;
    u16x8 vh;
#pragma unroll
    for (int i = 0; i < 8; i++) vh[i] = f2bf(src[base + i]);
    *(u16x8*)(Wb + (size_t)z * 65536 + base) = vh;
}

// ---------------- fused projection GEMM: all 3 z per block ----------------
// grid 512 = mBlk(128) x oBlk(4); block 256. Xh tile read 3x but L2-hot.
__global__ __launch_bounds__(256) void proj_gemm(
    const unsigned short* __restrict__ Xh,
    const unsigned short* __restrict__ Wb,
    const float* __restrict__ bq, const float* __restrict__ bk, const float* __restrict__ bv,
    unsigned short* __restrict__ Qt, unsigned short* __restrict__ Kt,
    unsigned short* __restrict__ Vn) {
    __shared__ unsigned short TL[64][136];
    int tid = threadIdx.x, lane = tid & 63, wv = tid >> 6;
    int l16 = lane & 15, lg = lane >> 4;
    int bid = blockIdx.x;
    int mBlk = bid & 127, oBlk = bid >> 7;

    int sBase = mBlk * 128 + (wv & 1) * 64;
    int oBase = oBlk * 64 + (wv >> 1) * 32;
    int b = mBlk >> 5;

    const unsigned short* Ah_p = Xh + (size_t)(sBase + l16) * 256 + lg * 8;
    const float* biases[3] = {bq, bk, bv};

    for (int z = 0; z < 3; z++) {
        const float* bias = biases[z];
        const unsigned short* Bh_p = Wb + (size_t)z * 65536 + (size_t)(oBase + l16) * 256 + lg * 8;

        f32x4 acc[4][2] = {};
        for (int kk = 0; kk < 8; kk++) {
            int ko = kk * 32;
            bf16x8 ah[4], bh[2];
#pragma unroll
            for (int mt = 0; mt < 4; mt++)
                ah[mt] = *(const bf16x8*)(Ah_p + mt * 16 * 256 + ko);
#pragma unroll
            for (int nt = 0; nt < 2; nt++)
                bh[nt] = *(const bf16x8*)(Bh_p + nt * 16 * 256 + ko);
#pragma unroll
            for (int mt = 0; mt < 4; mt++)
#pragma unroll
                for (int nt = 0; nt < 2; nt++)
                    acc[mt][nt] = __builtin_amdgcn_mfma_f32_16x16x32_bf16(ah[mt], bh[nt], acc[mt][nt], 0, 0, 0);
        }

        float b0 = bias[oBase + l16];
        float b1 = bias[oBase + 16 + l16];

        if (z < 2) {
            unsigned short* dst = (z == 0) ? Qt : Kt;
            float sc = (z == 1) ? (0.125f * LOG2E) : 1.0f;
            int head = oBlk;
            int d0 = (wv >> 1) * 32 + l16;
            size_t rowbase = ((size_t)(b * 4 + head)) * S_LEN;
#pragma unroll
            for (int mt = 0; mt < 4; mt++)
#pragma unroll
                for (int j = 0; j < 4; j++) {
                    int s = (mBlk & 31) * 128 + (wv & 1) * 64 + mt * 16 + lg * 4 + j;
                    size_t off = (rowbase + s) * HD;
                    dst[off + d0]      = f2bf((acc[mt][0][j] + b0) * sc);
                    dst[off + d0 + 16] = f2bf((acc[mt][1][j] + b1) * sc);
                }
        } else {
            // V -> tiled layout [bh][sTile(64)][d(64)][64] via LDS transpose
            int o0l = (wv >> 1) * 32 + l16;
#pragma unroll
            for (int mt = 0; mt < 4; mt++) {
                int sl = (wv & 1) * 64 + mt * 16 + lg * 4;
                *(unsigned int*)&TL[o0l][sl]          = cvt_pk_bf16(acc[mt][0][0] + b0, acc[mt][0][1] + b0);
                *(unsigned int*)&TL[o0l][sl + 2]      = cvt_pk_bf16(acc[mt][0][2] + b0, acc[mt][0][3] + b0);
                *(unsigned int*)&TL[o0l + 16][sl]     = cvt_pk_bf16(acc[mt][1][0] + b1, acc[mt][1][1] + b1);
                *(unsigned int*)&TL[o0l + 16][sl + 2] = cvt_pk_bf16(acc[mt][1][2] + b1, acc[mt][1][3] + b1);
            }
            __syncthreads();
            int ol = tid >> 2, sc0 = (tid & 3) * 32;
            int bhIdx = b * 4 + oBlk;
            int sbase = (mBlk & 31) * 128 + sc0;
            size_t obase = (size_t)bhIdx * 262144 + (size_t)ol * 64;
#pragma unroll
            for (int u = 0; u < 4; u++) {
                int s = sbase + u * 8;
                size_t addr = obase + (size_t)(s >> 6) * 4096 + (s & 63);
                u16x8 v = *(u16x8*)&TL[ol][sc0 + u * 8];
                *(u16x8*)(Vn + addr) = v;
            }
        }
    }
}

// ---------------- flash attention v11: [chunk][row] LDS, conflict-free b128 ----------------
// grid 512 = bh(16) x tblk(32) (XCD-swizzled); block 512 = 2 s-groups x 4 t-subwaves
// LDS 64KB: Q[g][p] at g*16K + p*8K; V[g][p] at 32K + g*16K + p*8K
// Tile layout: LDS[c*1024 + r*16] = G[r*128 + c*16]  (c = 16B chunk 0..7, r = row 0..63)
__global__ __launch_bounds__(512, 4) void attn_v11(const unsigned short* __restrict__ Qt,
                                                   const unsigned short* __restrict__ Kt,
                                                   const unsigned short* __restrict__ Vt2,
                                                   float* __restrict__ out) {
    __shared__ __align__(16) char smem[65536];
    int tid = threadIdx.x, lane = tid & 63, wv = tid >> 6;
    int l31 = lane & 31, h = lane >> 5;
    int g = wv >> 2, ws = wv & 3;

    int blk = blockIdx.x;
    int swz = (blk & 7) * 64 + (blk >> 3);   // 512 % 8 == 0: bijective
    int tblk = swz & 31, bh = swz >> 5;
    int t0 = tblk * 128 + ws * 32;

    // K fragments (B-operand): col t = t0+l31, k(d) = u*16 + h*8 + i (one-time gather)
    const unsigned short* kp = Kt + ((size_t)bh * S_LEN + t0 + l31) * HD + h * 8;
    bf16x8 kf[4];
#pragma unroll
    for (int u = 0; u < 4; u++) kf[u] = *(const bf16x8*)(kp + u * 16);

    const char* Qg = (const char*)(Qt + (size_t)bh * S_LEN * HD);   // 8KB per s-tile
    const char* Vg = (const char*)(Vt2 + (size_t)bh * 262144);      // 8KB per s-tile

    // staging source, pre-permuted for [chunk][row] LDS layout:
    // LDS q = ws*2048 + lane*16 (+1024)  ->  c = 2ws(+1), r = lane
    // global g = r*128 + c*16 = lane*128 + ws*32 (+16)
    int srcA = lane * 128 + ws * 32;
    int srcB = srcA + 16;

    char* Qbase = smem + g * 16384;
    char* Vbase = smem + 32768 + g * 16384;

    // fragment read: chunk c = u*2 + h at byte c<<10, row at l31*16 (+512 for rows 32-63)
    int ch[4];
#pragma unroll
    for (int u = 0; u < 4; u++) ch[u] = ((u * 2 + h) << 10);
    const int rowb = l31 * 16;
    const int rx = l31 & 7;   // epilogue scratch swizzle only

    f32x16 oacc0 = {}, oacc1 = {}, lacc = {};
    const f32x16 ZV = {};        // loop-invariant zero C-operand

    u16x8 ou;
#pragma unroll
    for (int i = 0; i < 8; i++) ou[i] = 0x3F80;
    bf16x8 ones = (bf16x8)ou;

#define STAGE11(p, t) do {                                  \
        const char* qg_ = Qg + (size_t)(t) * 8192;          \
        const char* vg_ = Vg + (size_t)(t) * 8192;          \
        gl16(qg_ + srcA, Qbase + (p) * 8192 + ws * 2048);         \
        gl16(qg_ + srcB, Qbase + (p) * 8192 + ws * 2048 + 1024);  \
        gl16(vg_ + srcA, Vbase + (p) * 8192 + ws * 2048);         \
        gl16(vg_ + srcB, Vbase + (p) * 8192 + ws * 2048 + 1024);  \
    } while (0)

    STAGE11(0, g);                 // group g's first tile
    __syncthreads();

    for (int it = 0; it < 32; ++it) {
        char* Qb = Qbase + (it & 1) * 8192;
        char* Vb = Vbase + (it & 1) * 8192;
        if (it < 31) STAGE11((it & 1) ^ 1, 2 * it + 2 + g);

        // ---- QK^T: D[s_row, t_col], two 32-row halves (log2-domain, K pre-scaled) ----
        __builtin_amdgcn_s_setprio(1);
        f32x16 s0, s1;
        {
            bf16x8 q = *(const bf16x8*)(Qb + ch[0] + rowb);
            s0 = __builtin_amdgcn_mfma_f32_32x32x16_bf16(q, kf[0], ZV, 0, 0, 0);
        }
#pragma unroll
        for (int u = 1; u < 4; u++) {
            bf16x8 q = *(const bf16x8*)(Qb + ch[u] + rowb);
            s0 = __builtin_amdgcn_mfma_f32_32x32x16_bf16(q, kf[u], s0, 0, 0, 0);
        }
        {
            bf16x8 q = *(const bf16x8*)(Qb + ch[0] + rowb + 512);
            s1 = __builtin_amdgcn_mfma_f32_32x32x16_bf16(q, kf[0], ZV, 0, 0, 0);
        }
#pragma unroll
        for (int u = 1; u < 4; u++) {
            bf16x8 q = *(const bf16x8*)(Qb + ch[u] + rowb + 512);
            s1 = __builtin_amdgcn_mfma_f32_32x32x16_bf16(q, kf[u], s1, 0, 0, 0);
        }
        __builtin_amdgcn_s_setprio(0);

        // ---- P = exp2(s) raw (v_exp_f32): common scale cancels in the ratio ----
#pragma unroll
        for (int r = 0; r < 16; r++) {
            s0[r] = __builtin_amdgcn_exp2f(s0[r]);
            s1[r] = __builtin_amdgcn_exp2f(s1[r]);
        }

        // ---- P -> bf16 B-fragments in-register (cvt_pk + permlane32_swap) ----
        unsigned int W0[4][2], W1[4][2];
#pragma unroll
        for (int q = 0; q < 4; q++)
#pragma unroll
            for (int ip = 0; ip < 2; ip++) {
                W0[q][ip] = cvt_pk_bf16(s0[4 * q + 2 * ip], s0[4 * q + 2 * ip + 1]);
                W1[q][ip] = cvt_pk_bf16(s1[4 * q + 2 * ip], s1[4 * q + 2 * ip + 1]);
            }
        u32x4 pw0, pw1, pw2, pw3;
        {
            unsigned int a0 = W0[0][0], b0 = W0[1][0]; PLSWAP(a0, b0);
            unsigned int a1 = W0[0][1], b1 = W0[1][1]; PLSWAP(a1, b1);
            pw0 = (u32x4){a0, a1, b0, b1};
            unsigned int c0s = W0[2][0], d0s = W0[3][0]; PLSWAP(c0s, d0s);
            unsigned int c1s = W0[2][1], d1s = W0[3][1]; PLSWAP(c1s, d1s);
            pw1 = (u32x4){c0s, c1s, d0s, d1s};
            unsigned int e0 = W1[0][0], f0 = W1[1][0]; PLSWAP(e0, f0);
            unsigned int e1 = W1[0][1], f1 = W1[1][1]; PLSWAP(e1, f1);
            pw2 = (u32x4){e0, e1, f0, f1};
            unsigned int g0 = W1[2][0], h0 = W1[3][0]; PLSWAP(g0, h0);
            unsigned int g1 = W1[2][1], h1 = W1[3][1]; PLSWAP(g1, h1);
            pw3 = (u32x4){g0, g1, h0, h1};
        }
        bf16x8 pb0 = *(bf16x8*)&pw0, pb1 = *(bf16x8*)&pw1;
        bf16x8 pb2 = *(bf16x8*)&pw2, pb3 = *(bf16x8*)&pw3;

        // ---- O += V . P (D[d_row, t_col]) + l-sum via ones-MFMA (MFMA pipe has slack) ----
        __builtin_amdgcn_s_setprio(1);
#pragma unroll
        for (int b2 = 0; b2 < 4; b2++) {
            bf16x8 pb = (b2 == 0) ? pb0 : (b2 == 1) ? pb1 : (b2 == 2) ? pb2 : pb3;
            bf16x8 v0 = *(const bf16x8*)(Vb + ch[b2] + rowb);
            bf16x8 v1 = *(const bf16x8*)(Vb + ch[b2] + rowb + 512);
            oacc0 = __builtin_amdgcn_mfma_f32_32x32x16_bf16(v0, pb, oacc0, 0, 0, 0);
            oacc1 = __builtin_amdgcn_mfma_f32_32x32x16_bf16(v1, pb, oacc1, 0, 0, 0);
            lacc  = __builtin_amdgcn_mfma_f32_32x32x16_bf16(ones, pb, lacc, 0, 0, 0);
        }
        __builtin_amdgcn_s_setprio(0);

        __syncthreads();  // staged tile ready (vmcnt drained) + reads of Qb/Vb done
    }

    // ---- merge the two s-groups via LDS (plain sums — no max state) ----
    float l = lacc[0];
    if (g == 1) {
        float* ml = (float*)(smem + ws * 256);
        ml[lane] = l;
        float* ob = (float*)(smem + 32768 + ws * 8192) + lane * 32;
#pragma unroll
        for (int r = 0; r < 16; r++) {
            ob[(((r >> 2) ^ rx) << 2) + (r & 3)]       = oacc0[r];
            ob[((((r >> 2) + 4) ^ rx) << 2) + (r & 3)] = oacc1[r];
        }
    }
    __syncthreads();
    if (g == 0) {
        const float* ml = (const float*)(smem + ws * 256);
        float lB = ml[lane];
        const float* ob = (const float*)(smem + 32768 + ws * 8192) + lane * 32;
        float rinv = 1.0f / (l + lB);

        float* op = out + (size_t)(bh * 64) * S_LEN + t0 + l31;
#pragma unroll
        for (int r = 0; r < 16; r++) {
            int d = (r & 3) + 8 * (r >> 2) + 4 * h;
            float vB0 = ob[(((r >> 2) ^ rx) << 2) + (r & 3)];
            float vB1 = ob[((((r >> 2) + 4) ^ rx) << 2) + (r & 3)];
            op[(size_t)d * S_LEN]        = (oacc0[r] + vB0) * rinv;
            op[(size_t)(d + 32) * S_LEN] = (oacc1[r] + vB1) * rinv;
        }
    }
}

extern "C" void kernel_launch(void* const* d_in, const int* in_sizes, int n_in,
                              void* d_out, int out_size, void* d_ws, size_t ws_size,
                              hipStream_t stream) {
    const float* X  = (const float*)d_in[0];
    const float* Wq = (const float*)d_in[1];
    const float* bq = (const float*)d_in[2];
    const float* Wk = (const float*)d_in[3];
    const float* bk = (const float*)d_in[4];
    const float* Wv = (const float*)d_in[5];
    const float* bv = (const float*)d_in[6];
    float* out = (float*)d_out;

    const size_t ELEMS = (size_t)16 * S_LEN * HD;
    unsigned short* Qt = (unsigned short*)d_ws;
    unsigned short* Kt = Qt + ELEMS;
    unsigned short* Vn = Kt + ELEMS;
    unsigned short* Wb = Vn + ELEMS;   // 3*65536 u16

    unsigned short* Xh = (unsigned short*)d_out;   // consumed before attn writes out

    cvtX<<<1024, 256, 0, stream>>>(X, Xh);
    cvtW<<<96, 256, 0, stream>>>(Wq, Wk, Wv, Wb);
    proj_gemm<<<512, 256, 0, stream>>>(Xh, Wb, bq, bk, bv, Qt, Kt, Vn);
    attn_v11<<<512, 512, 0, stream>>>(Qt, Kt, Vn, out);
}